// Round 3
// baseline (406.066 us; speedup 1.0000x reference)
//
#include <hip/hip_runtime.h>
#include <stdint.h>

// BilinearScorer: out[n,r] = sum_{h,k} pred[n,h] U[h,r,k] args[n,k] + bias1[r,:].args[n,:] + bias2[r]
// n=4096, h=k=512, R=64.  137.4 GFLOP fp32-equivalent.
// R3: fp16 MFMA (R2 numerics, absmax 0.25 passes) with restructured K-loop:
//  - BK=64, phased frags: 32 MFMA per barrier round (R2: 16) -> halved barrier drains
//  - block owns full N=512 for one (m-tile, role): 4 n-strips, LDS reduction,
//    zero global atomics, prologue/fill amortized over 32 rounds (R2: 16)
//  - XOR swizzle slot = chunk ^ (row&7): every 8 consecutive lanes cover all 8
//    bank groups (R2-verified invariant, SQ_LDS_BANK_CONFLICT == 0)

#define HID   512
#define ROLES 64
#define NTOK  4096
#define BM    128
#define BK    64

typedef __attribute__((ext_vector_type(8))) _Float16 f16x8;  // MFMA A/B operand: 4 VGPRs
typedef __attribute__((ext_vector_type(4))) _Float16 f16x4;
typedef __attribute__((ext_vector_type(4))) float    f32x4;

__device__ __forceinline__ void async16(const void* g, void* l) {
  // global -> LDS direct copy, 16B/lane. LDS dest is wave-uniform base + lane*16;
  // per-lane SOURCE address is free (implements the store-side swizzle).
  __builtin_amdgcn_global_load_lds(
      (const __attribute__((address_space(1))) uint32_t*)g,
      (__attribute__((address_space(3))) uint32_t*)l, 16, 0, 0);
}

// ---- prep: pred fp32 -> fp16 ----------------------------------------------
__global__ __launch_bounds__(256) void cvt_pred(const float* __restrict__ in,
                                                _Float16* __restrict__ out) {
  const int idx = blockIdx.x * 256 + threadIdx.x;        // NTOK*HID/4 threads
  const float4 v = ((const float4*)in)[idx];
  f16x4 o;
  o[0] = (_Float16)v.x; o[1] = (_Float16)v.y;
  o[2] = (_Float16)v.z; o[3] = (_Float16)v.w;
  ((f16x4*)out)[idx] = o;
}

// ---- prep: U[h][r][k] -> Ut[r][k][h] fp16 (B-frags h-contiguous) ----------
__global__ __launch_bounds__(256) void cvt_u(const float* __restrict__ U,
                                             _Float16* __restrict__ ut) {
  __shared__ float tile[64][65];                 // +1 pad breaks bank conflicts
  const int h0 = blockIdx.x * 64, n0 = blockIdx.y * 64, r = blockIdx.z;
  const int t = threadIdx.x;
  const int jc = (t & 15) * 4;
#pragma unroll
  for (int ii = 0; ii < 4; ii++) {
    const int i = ii * 16 + (t >> 4);            // h-row within tile
    const float4 v = *(const float4*)(U + ((size_t)(h0 + i) * ROLES + r) * HID + n0 + jc);
    tile[i][jc + 0] = v.x; tile[i][jc + 1] = v.y;
    tile[i][jc + 2] = v.z; tile[i][jc + 3] = v.w;
  }
  __syncthreads();
  const int j = t >> 2, hc = (t & 3) * 16;       // write row n0+j, 16 h values
  const size_t ob = ((size_t)r * HID + n0 + j) * HID + h0 + hc;
  alignas(16) _Float16 hb[16];
#pragma unroll
  for (int q = 0; q < 16; q++) hb[q] = (_Float16)tile[hc + q][j];
  *(uint4*)(ut + ob)     = *(const uint4*)hb;
  *(uint4*)(ut + ob + 8) = *(const uint4*)(hb + 8);
}

// ---- main fused GEMM ------------------------------------------------------
__global__ __launch_bounds__(256, 3) void bilinear_mfma(
    const _Float16* __restrict__ predf, const _Float16* __restrict__ utf,
    const float* __restrict__ args, const float* __restrict__ bias1,
    const float* __restrict__ bias2, float* __restrict__ out) {
  __shared__ _Float16 sA[BM * BK];               // 16 KB
  __shared__ _Float16 sB[BM * BK];               // 16 KB
  __shared__ float sred[BM];                     // 512 B

  const int r = blockIdx.x, mblk = blockIdx.y;
  const int m0 = mblk * BM;
  const int tid  = threadIdx.x;
  const int wave = tid >> 6, lane = tid & 63;
  const int col  = lane & 15, quad = lane >> 4;
  const int wm = (wave & 1) * 64, wn = (wave >> 1) * 64;

  if (tid < BM) sred[tid] = 0.f;                 // first K-loop barrier publishes this

  // staging: tile = 128 rows x 64 f16 (128B/row) = 1024 x 16B chunks, 4 calls.
  // call c covers linear chunks c*256 + tid; row = chunk>>3, slot = chunk&7;
  // slot holds global chunk (slot ^ (row&7)).
  const int i_loc = tid >> 3;                    // row 0..31 within call (+32c)
  const int ko    = ((tid & 7) ^ (i_loc & 7)) * 8;
  const size_t offA = (size_t)(m0 + i_loc) * HID + ko;
  const int ldsW = wave * 512;                   // f16 elems (64 chunks/wave/call)

  // reader slots: row&7 == col&7 for all frag rows (wm,16*mt ≡ 0 mod 8)
  const int slotL8 = (quad ^ (col & 7)) * 8;     // k-chunk quad   (k in [0,32))
  const int slotH8 = slotL8 ^ 32;                // k-chunk quad+4 (k in [32,64))
  int rowA[4], rowB[4];
#pragma unroll
  for (int mt = 0; mt < 4; mt++) rowA[mt] = (wm + mt * 16 + col) * BK;
#pragma unroll
  for (int nt = 0; nt < 4; nt++) rowB[nt] = (wn + nt * 16 + col) * BK;

  for (int ns = 0; ns < 4; ns++) {
    const int n0 = ns * 128;
    const size_t offB = ((size_t)r * HID + n0 + i_loc) * HID + ko;

    f32x4 acc[4][4];
#pragma unroll
    for (int a = 0; a < 4; a++)
#pragma unroll
      for (int b = 0; b < 4; b++) acc[a][b] = (f32x4){0.f, 0.f, 0.f, 0.f};

    for (int k0 = 0; k0 < HID; k0 += BK) {
#pragma unroll
      for (int c = 0; c < 4; c++) {
        async16(predf + offA + (size_t)(c * 32) * HID + k0, sA + c * 2048 + ldsW);
        async16(utf   + offB + (size_t)(c * 32) * HID + k0, sB + c * 2048 + ldsW);
      }
      __syncthreads();                           // drains vmcnt (staging done)

      {                                          // phase 0: k in [k0, k0+32)
        f16x8 a[4], b[4];
#pragma unroll
        for (int mt = 0; mt < 4; mt++) a[mt] = *(const f16x8*)(sA + rowA[mt] + slotL8);
#pragma unroll
        for (int nt = 0; nt < 4; nt++) b[nt] = *(const f16x8*)(sB + rowB[nt] + slotL8);
#pragma unroll
        for (int mt = 0; mt < 4; mt++)
#pragma unroll
          for (int nt = 0; nt < 4; nt++)
            acc[mt][nt] = __builtin_amdgcn_mfma_f32_16x16x32_f16(a[mt], b[nt], acc[mt][nt], 0, 0, 0);
      }
      {                                          // phase 1: k in [k0+32, k0+64)
        f16x8 a[4], b[4];
#pragma unroll
        for (int mt = 0; mt < 4; mt++) a[mt] = *(const f16x8*)(sA + rowA[mt] + slotH8);
#pragma unroll
        for (int nt = 0; nt < 4; nt++) b[nt] = *(const f16x8*)(sB + rowB[nt] + slotH8);
#pragma unroll
        for (int mt = 0; mt < 4; mt++)
#pragma unroll
          for (int nt = 0; nt < 4; nt++)
            acc[mt][nt] = __builtin_amdgcn_mfma_f32_16x16x32_f16(a[mt], b[nt], acc[mt][nt], 0, 0, 0);
      }
      __syncthreads();
    }

    // strip epilogue: s[m] += sum_n (T[m,n] + bias1[r,n]) * args[m,n]
    float b1v[4];
#pragma unroll
    for (int nt = 0; nt < 4; nt++)
      b1v[nt] = bias1[r * HID + n0 + wn + nt * 16 + col];

#pragma unroll
    for (int mt = 0; mt < 4; mt++) {
#pragma unroll
      for (int reg = 0; reg < 4; reg++) {
        const int mrow = wm + mt * 16 + quad * 4 + reg;   // C/D row = quad*4+reg (m89)
        const float* arow = args + (size_t)(m0 + mrow) * HID + n0 + wn + col;
        float s = 0.f;
#pragma unroll
        for (int nt = 0; nt < 4; nt++)
          s += (acc[mt][nt][reg] + b1v[nt]) * arow[nt * 16];
        s += __shfl_xor(s, 1);
        s += __shfl_xor(s, 2);
        s += __shfl_xor(s, 4);
        s += __shfl_xor(s, 8);                   // reduce 16-lane col group
        if (col == 0) atomicAdd(&sred[mrow], s); // LDS atomic; waves 0&2 / 1&3 pair up
      }
    }
  }

  __syncthreads();
  if (tid < BM)
    out[(size_t)(m0 + tid) * ROLES + r] = sred[tid] + bias2[r];
}

// ---- correctness fallback if workspace is too small (slow, pure fp32) -----
__global__ __launch_bounds__(256) void fallback_k(
    const float* __restrict__ pred, const float* __restrict__ args,
    const float* __restrict__ U, const float* __restrict__ b1,
    const float* __restrict__ b2, float* __restrict__ out) {
  const int idx = blockIdx.x * 256 + threadIdx.x;   // 262144
  const int r = idx >> 12;                          // block-uniform role
  const int n = idx & (NTOK - 1);
  const float* arow = args + (size_t)n * HID;
  const float* prow = pred + (size_t)n * HID;
  float acc = 0.f;
  for (int h = 0; h < HID; h++) {
    const float* urow = U + ((size_t)h * ROLES + r) * HID;
    float s = 0.f;
    for (int k = 0; k < HID; k++) s = fmaf(urow[k], arow[k], s);
    acc = fmaf(prow[h], s, acc);
  }
  float sb = 0.f;
  const float* brow = b1 + (size_t)r * HID;
  for (int k = 0; k < HID; k++) sb = fmaf(brow[k], arow[k], sb);
  out[(size_t)n * ROLES + r] = acc + sb + b2[r];
}

extern "C" void kernel_launch(void* const* d_in, const int* in_sizes, int n_in,
                              void* d_out, int out_size, void* d_ws, size_t ws_size,
                              hipStream_t stream) {
  const float* pred = (const float*)d_in[0];
  const float* args = (const float*)d_in[1];
  const float* U    = (const float*)d_in[2];
  const float* b1   = (const float*)d_in[3];
  const float* b2   = (const float*)d_in[4];
  float* out = (float*)d_out;

  const size_t PRED_ELEMS = (size_t)NTOK * HID;         // 2,097,152
  const size_t U_ELEMS    = (size_t)HID * ROLES * HID;  // 16,777,216
  const size_t WS_NEEDED  = (PRED_ELEMS + U_ELEMS) * sizeof(_Float16); // ~36 MiB

  if (ws_size < WS_NEEDED) {
    hipLaunchKernelGGL(fallback_k, dim3((NTOK * ROLES) / 256), dim3(256), 0, stream,
                       pred, args, U, b1, b2, out);
    return;
  }

  _Float16* predf = (_Float16*)d_ws;
  _Float16* utf   = predf + PRED_ELEMS;

  hipLaunchKernelGGL(cvt_pred, dim3((unsigned)(PRED_ELEMS / 4 / 256)), dim3(256), 0, stream,
                     pred, predf);
  hipLaunchKernelGGL(cvt_u, dim3(HID / 64, HID / 64, ROLES), dim3(256), 0, stream,
                     U, utf);
  hipLaunchKernelGGL(bilinear_mfma, dim3(ROLES, NTOK / BM), dim3(256), 0, stream,
                     predf, utf, args, b1, b2, out);
}